// Round 12
// baseline (134.001 us; speedup 1.0000x reference)
//
#include <hip/hip_runtime.h>
#include <cstdint>
#include <cfloat>
#include <math.h>

// Problem constants (match reference)
#define BB 16
#define SS 64
#define VV 50257
#define PP 64

#define NT 1024         // threads per block (16 waves; 2 blocks/CU -> 32 waves/CU)
#define HNT 256         // mid-phase crew: waves 0-3 (verified correct in R11)
#define NWH (HNT / 64)  // 4 mid waves
#define SNT (NT - HNT)  // 768 streaming threads (waves 4-15)
#define NBLK 512        // block g handles rows g and g+512 (same s, same prev!)
#define BINS 2048       // key histogram bins (top 11 bits of ordered key)
#define CAP 1536        // candidate buffer capacity
#define BMW 1572        // bitmap words: ceil(50257/32)=1571 (+1 pad)
#define KCAP 128        // kept (top-k survivors) capacity
#define BCAP 512        // kth-bin member list capacity
#define TRAW 6.0f       // raw-domain candidate threshold (= 7.5 scaled * 0.8)

typedef float f32x4 __attribute__((ext_vector_type(4)));

// monotone float->uint key (increasing)
__device__ __forceinline__ uint32_t fkey(float f) {
    uint32_t u = __float_as_uint(f);
    return u ^ ((uint32_t)((int32_t)u >> 31) | 0x80000000u);
}
__device__ __forceinline__ float key2f(uint32_t u) {
    uint32_t b = (u & 0x80000000u) ? (u ^ 0x80000000u) : ~u;
    return __uint_as_float(b);
}

__global__ __launch_bounds__(NT)
void sch_kernel(const float* __restrict__ logits,
                const int* __restrict__ prev,
                float* __restrict__ out)
{
    const int g   = blockIdx.x;            // 0..511
    const int rA  = g;
    const int rB  = g + NBLK;
    const int s   = g % SS;                // rA%SS == rB%SS (512 % 64 == 0)
    const int bA  = rA / SS;
    const int bB  = rB / SS;
    const int tid = threadIdx.x;
    const float* rowA  = logits + (size_t)rA * VV;
    const float* rowB  = logits + (size_t)rB * VV;
    float*       orowA = out    + (size_t)rA * VV;
    float*       orowB = out    + (size_t)rB * VV;

    __shared__ uint32_t s_bm[BMW];
    __shared__ float    s_cv[CAP];    // row-A candidates (pre-temperature domain)
    __shared__ int      s_ci[CAP];
    __shared__ float    s_cv2[CAP];   // row-B candidates
    __shared__ int      s_ci2[CAP];
    __shared__ uint32_t s_hist[BINS];
    __shared__ uint32_t s_scan[2 * NWH];
    __shared__ int      s_ptok[PP];
    __shared__ int      s_pneg[PP];   // all_neg flag (same for both rows: same s)
    __shared__ float    s_prawA[PP];
    __shared__ float    s_prawB[PP];
    __shared__ float    s_ppenA[PP];
    __shared__ float    s_ppenB[PP];
    __shared__ float    s_binv[BCAP];
    __shared__ double   s_v64[KCAP];
    __shared__ double   s_e64[KCAP];
    __shared__ int      s_ki[KCAP];
    __shared__ float    s_kof[KCAP];
    __shared__ int      s_kiA[KCAP];  // saved row-A scatter list
    __shared__ float    s_kofA[KCAP];
    __shared__ int    s_cnt, s_cnt2, s_cntinv, s_b50, s_need, s_cntb, s_k50, s_kp, s_Kk;
    __shared__ int    s_hbar;         // half-barrier counter (monotone)
    __shared__ float  s_kth, s_rc;
    __shared__ double s_lse;

    // ---------------- phase 0: penalty setup, ONCE for both rows ----------------
    for (int i = tid; i < BMW; i += NT) s_bm[i] = 0u;
    if (tid < PP) s_pneg[tid] = 1;
    if (tid == 0) { s_cnt = 0; s_cnt2 = 0; s_cntinv = 0; s_hbar = 0; }
    __syncthreads();
    for (int pair = tid; pair < PP * BB; pair += NT) {
        int ti = pair & (PP - 1);
        int b2 = pair >> 6;
        int tok = prev[s * PP + ti];
        float gg = logits[((size_t)b2 * SS + s) * (size_t)VV + tok];
        if (gg >= 0.f) atomicAnd(&s_pneg[ti], 0);
        if (b2 == 0)  s_ptok[ti]  = tok;
        if (b2 == bA) s_prawA[ti] = gg;
        if (b2 == bB) s_prawB[ti] = gg;
    }
    __syncthreads();
    if (tid < PP) {
        int neg = s_pneg[tid];
        float ga = s_prawA[tid], gb = s_prawB[tid];
        s_ppenA[tid] = neg ? (ga * 1.2f) : (ga / 1.2f);
        s_ppenB[tid] = neg ? (gb * 1.2f) : (gb / 1.2f);
        int tok = s_ptok[tid];
        atomicOr(&s_bm[tok >> 5], 1u << (tok & 31));
    }
    __syncthreads();

    // ---------------- half-barrier (waves 0-NWH only; spin on LDS) ----------------
    int hb_phase = 0;
    auto halfbar = [&]() {
        __threadfence_block();
        if ((tid & 63) == 0) atomicAdd(&s_hbar, 1);
        ++hb_phase;
        while (*(volatile int*)&s_hbar < NWH * hb_phase)
            __builtin_amdgcn_s_sleep(1);
        __threadfence_block();
    };

    // ---------------- generic helpers ----------------
    auto kbit = [&](int t) -> uint32_t {
        return (s_bm[t >> 5] >> (t & 31)) & 1u;
    };
    auto addRawP = [&](int t, float raw, float* cv, int* ci, int* pcnt) {
        if (raw >= TRAW) {
            int pos = atomicAdd(pcnt, 1);
            if (pos < CAP) { cv[pos] = raw; ci[pos] = t; }
        }
    };
    auto geomNq = [&](const void* p) -> int {
        int mis = (int)(((size_t)p >> 2) & 3);
        int head = (4 - mis) & 3;
        return (VV - head) >> 2;
    };
    // static strided read of quad segment [qlo, qhi); optional head/tail scalars
    auto streamSeg = [&](const float* row_, float* cv, int* ci, int* pcnt,
                         int qlo, int qhi, int t0, int nthr, bool doHT) {
        const int mis   = (int)(((size_t)row_ >> 2) & 3);
        const int head  = (4 - mis) & 3;
        const int nq    = (VV - head) >> 2;
        const int ttail = head + (nq << 2);
        const float4* p4 = reinterpret_cast<const float4*>(row_ + head);
        if (doHT) {
            for (int t = t0; t < head; t += nthr) addRawP(t, row_[t], cv, ci, pcnt);
            for (int t = ttail + t0; t < VV; t += nthr) addRawP(t, row_[t], cv, ci, pcnt);
        }
        int base = qlo;
        for (; base + 4 * nthr <= qhi; base += 4 * nthr) {
            float4 f[4];
            #pragma unroll
            for (int u = 0; u < 4; ++u) f[u] = p4[base + t0 + u * nthr];
            #pragma unroll
            for (int u = 0; u < 4; ++u) {
                int t = head + ((base + t0 + u * nthr) << 2);
                addRawP(t + 0, f[u].x, cv, ci, pcnt);
                addRawP(t + 1, f[u].y, cv, ci, pcnt);
                addRawP(t + 2, f[u].z, cv, ci, pcnt);
                addRawP(t + 3, f[u].w, cv, ci, pcnt);
            }
        }
        for (int q = base + t0; q < qhi; q += nthr) {
            float4 f = p4[q];
            int t = head + (q << 2);
            addRawP(t + 0, f.x, cv, ci, pcnt);
            addRawP(t + 1, f.y, cv, ci, pcnt);
            addRawP(t + 2, f.z, cv, ci, pcnt);
            addRawP(t + 3, f.w, cv, ci, pcnt);
        }
    };
    // static strided nt-fill of quad segment [qlo, qhi); optional head/tail
    auto fillSeg = [&](float* orow_, float rc_, int qlo, int qhi,
                       int t0, int nthr, bool doHT) {
        const int omis   = (int)(((size_t)orow_ >> 2) & 3);
        const int ohead  = (4 - omis) & 3;
        const int onq    = (VV - ohead) >> 2;
        const int ottail = ohead + (onq << 2);
        f32x4* o4 = reinterpret_cast<f32x4*>(orow_ + ohead);
        f32x4 rc4; rc4.x = rc_; rc4.y = rc_; rc4.z = rc_; rc4.w = rc_;
        if (doHT) {
            for (int t = t0; t < ohead; t += nthr)
                __builtin_nontemporal_store(rc_, &orow_[t]);
            for (int t = ottail + t0; t < VV; t += nthr)
                __builtin_nontemporal_store(rc_, &orow_[t]);
        }
        for (int q = qlo + t0; q < qhi; q += nthr)
            __builtin_nontemporal_store(rc4, &o4[q]);
    };

    // ======== mid-phase machinery on waves 0-NWH (halfbar-synced) ========
    auto procFullH = [&](int t, float raw, bool doHist, float thr, const float* ppenS,
                         float* cv, int* ci, int* pcnt) {
        float v = raw;
        if (kbit(t)) {
            #pragma unroll 1
            for (int j = 0; j < PP; ++j)
                if (s_ptok[j] == t) { v = ppenS[j]; break; }
        }
        if (!doHist) {
            if (v >= thr) {
                int pos = atomicAdd(pcnt, 1);
                if (pos < CAP) { cv[pos] = v; ci[pos] = t; }
            }
        } else {
            atomicAdd(&s_hist[fkey(v) >> 21], 1u);
        }
    };
    auto streamFullH = [&](bool doHist, float thr, const float* row_, const float* ppenS,
                           float* cv, int* ci, int* pcnt) {
        const int mis   = (int)(((size_t)row_ >> 2) & 3);
        const int head  = (4 - mis) & 3;
        const int nq    = (VV - head) >> 2;
        const int ttail = head + (nq << 2);
        const float4* p4 = reinterpret_cast<const float4*>(row_ + head);
        for (int t = tid; t < head; t += HNT) procFullH(t, row_[t], doHist, thr, ppenS, cv, ci, pcnt);
        for (int q = tid; q < nq; q += HNT) {
            float4 f = p4[q];
            int t = head + (q << 2);
            procFullH(t + 0, f.x, doHist, thr, ppenS, cv, ci, pcnt);
            procFullH(t + 1, f.y, doHist, thr, ppenS, cv, ci, pcnt);
            procFullH(t + 2, f.z, doHist, thr, ppenS, cv, ci, pcnt);
            procFullH(t + 3, f.w, doHist, thr, ppenS, cv, ci, pcnt);
        }
        for (int t = ttail + tid; t < VV; t += HNT) procFullH(t, row_[t], doHist, thr, ppenS, cv, ci, pcnt);
    };
    auto findB50H = [&](int target) {
        halfbar();                           // histogram complete
        const int per = BINS / HNT;          // 8 bins per thread
        int base = tid * per;
        uint32_t loc = 0;
        #pragma unroll
        for (int k2 = 0; k2 < per; ++k2) loc += s_hist[base + k2];
        uint32_t incl = loc;
        #pragma unroll
        for (int off = 1; off < 64; off <<= 1) {
            uint32_t u = (uint32_t)__shfl_up((int)incl, off, 64);
            if ((tid & 63) >= off) incl += u;
        }
        int wid = tid >> 6;                  // 0..NWH-1
        if ((tid & 63) == 63) s_scan[wid] = incl;
        halfbar();
        if (tid < NWH) {
            uint32_t p = 0;
            for (int w = 0; w < tid; ++w) p += s_scan[w];
            s_scan[NWH + tid] = p;
        }
        halfbar();
        uint32_t pre_incl = s_scan[NWH + wid] + incl;
        uint32_t total    = s_scan[NWH + NWH - 1] + s_scan[NWH - 1];
        uint32_t run = total - pre_incl;
        for (int k2 = per - 1; k2 >= 0; --k2) {
            uint32_t h = s_hist[base + k2];
            uint32_t run2 = run + h;
            if (run < (uint32_t)target && run2 >= (uint32_t)target) {
                s_b50 = base + k2;
                s_need = target - (int)run;
            }
            run = run2;
        }
        halfbar();
    };
    auto doFallbackH = [&](const float* row_, const float* ppenS,
                           float* cv, int* ci, int* pcnt) {
        for (int i = tid; i < BINS; i += HNT) s_hist[i] = 0u;
        halfbar();
        streamFullH(true, 0.f, row_, ppenS, cv, ci, pcnt);
        findB50H(50);
        float thrF = key2f((uint32_t)s_b50 << 21);
        if (tid == 0) *pcnt = 0;
        halfbar();
        streamFullH(false, thrF, row_, ppenS, cv, ci, pcnt);
        halfbar();
    };
    auto computeKthH = [&](float* cv, int* pcnt) {
        for (int i = tid; i < BINS; i += HNT) s_hist[i] = 0u;
        if (tid == 0) { s_cntb = 0; s_kth = -FLT_MAX; }
        halfbar();
        int cc = min(*pcnt, CAP);
        for (int i = tid; i < cc; i += HNT)
            atomicAdd(&s_hist[fkey(cv[i]) >> 21], 1u);
        findB50H(50);
        int b50 = s_b50, need = s_need;
        for (int i = tid; i < cc; i += HNT) {
            if ((int)(fkey(cv[i]) >> 21) == b50) {
                int p = atomicAdd(&s_cntb, 1);
                if (p < BCAP) s_binv[p] = cv[i];
            }
        }
        halfbar();
        int cb = min(s_cntb, BCAP);
        for (int i = tid; i < cb; i += HNT) {
            float vi = s_binv[i];
            int gt = 0, ge = 0;
            for (int j = 0; j < cb; ++j) {
                float vj = s_binv[j];
                gt += (vj > vi);
                ge += (vj >= vi);
            }
            if (gt < need && ge >= need) s_kth = vi;   // benign race: same value
        }
        halfbar();
    };
    // mid phases on waves 0-NWH. Decision arithmetic identical to R9/R10/R11.
    auto midPhasesH = [&](const float* row_, const float* prawS, const float* ppenS,
                          float* cv, int* ci, int* pcnt) {
        const int cntRaw = min(*pcnt, CAP);
        for (int i = tid; i < cntRaw; i += HNT) {
            if (kbit(ci[i])) {
                cv[i] = -FLT_MAX;
                atomicAdd(&s_cntinv, 1);
            }
        }
        halfbar();
        if (tid < PP) {
            int tok = s_ptok[tid];
            bool first = true;
            for (int j = 0; j < tid; ++j)
                if (s_ptok[j] == tok) { first = false; break; }
            if (first) {
                int pos = atomicAdd(pcnt, 1);
                if (pos < CAP) { cv[pos] = ppenS[tid]; ci[pos] = tok; }
            }
        }
        halfbar();
        bool fellback = false;
        {
            bool okc = (*pcnt <= CAP) && ((cntRaw - s_cntinv) >= 50);
            if (!okc) { doFallbackH(row_, ppenS, cv, ci, pcnt); fellback = true; }
        }
        computeKthH(cv, pcnt);
        if (!fellback && (s_kth - 1e-4f < TRAW)) {
            doFallbackH(row_, ppenS, cv, ci, pcnt);
            computeKthH(cv, pcnt);
        }
        if (tid == 0) s_k50 = 0;
        halfbar();
        const float gthr = s_kth - 1e-4f;
        const int cntc = min(*pcnt, CAP);
        for (int i = tid; i < cntc; i += HNT) {
            if (cv[i] >= gthr) {
                int p = atomicAdd(&s_k50, 1);
                if (p < KCAP) {
                    int tok = ci[i];
                    double v64;
                    if (kbit(tok)) {
                        int pj = 0;
                        #pragma unroll 1
                        for (int j = 0; j < PP; ++j)
                            if (s_ptok[j] == tok) { pj = j; break; }
                        double gd = (double)prawS[pj];
                        double pen = s_pneg[pj] ? (gd * 1.2) : (gd / 1.2);
                        v64 = pen / 0.8;
                    } else {
                        v64 = (double)cv[i] / 0.8;
                    }
                    s_v64[p] = v64;
                    s_ki[p]  = tok;
                }
            }
        }
        halfbar();
        const int k50c = min(s_k50, KCAP);
        for (int i = k50c + tid; i < KCAP; i += HNT) {
            s_v64[i] = -1e300;
            s_ki[i]  = (1 << 30) + i;
        }
        halfbar();
        // single-wave register bitonic sort (identical comparator)
        if (tid < 64) {
            int l = tid;
            double v0 = s_v64[l],    v1 = s_v64[l + 64];
            int    i0 = s_ki[l],     i1 = s_ki[l + 64];
            for (int k = 2; k <= KCAP; k <<= 1) {
                for (int j = k >> 1; j > 0; j >>= 1) {
                    if (j >= 64) {
                        bool before = (v0 > v1) || (v0 == v1 && i0 < i1);
                        if (!before) {
                            double tv = v0; v0 = v1; v1 = tv;
                            int    ti = i0; i0 = i1; i1 = ti;
                        }
                    } else {
                        double nv0 = __shfl_xor(v0, j, 64);
                        double nv1 = __shfl_xor(v1, j, 64);
                        int    ni0 = __shfl_xor(i0, j, 64);
                        int    ni1 = __shfl_xor(i1, j, 64);
                        bool lower = ((l & j) == 0);
                        bool up0 = ((l & k) == 0);
                        bool up1 = (((l + 64) & k) == 0);
                        bool bm0 = (v0 > nv0) || (v0 == nv0 && i0 < ni0);
                        bool bm1 = (v1 > nv1) || (v1 == nv1 && i1 < ni1);
                        bool keep0 = lower ? (up0 == bm0) : (up0 != bm0);
                        bool keep1 = lower ? (up1 == bm1) : (up1 != bm1);
                        if (!keep0) { v0 = nv0; i0 = ni0; }
                        if (!keep1) { v1 = nv1; i1 = ni1; }
                    }
                }
            }
            s_v64[l] = v0; s_v64[l + 64] = v1;
            s_ki[l]  = i0; s_ki[l + 64]  = i1;
        }
        halfbar();
        if (tid == 0) {
            int kk = k50c;
            int Kkept;
            if (kk <= 50) Kkept = kk;
            else {
                double kth64 = s_v64[49];
                Kkept = 50;
                while (Kkept < kk && s_v64[Kkept] == kth64) ++Kkept;
            }
            s_Kk = Kkept;
        }
        halfbar();
        const int Kk = s_Kk;
        const double mx = s_v64[0];
        if (tid < Kk) s_e64[tid] = exp(s_v64[tid] - mx);
        halfbar();
        if (tid == 0) {
            double D = 0.0;                    // same serial order as reference
            #pragma unroll 1
            for (int i = 0; i < Kk; ++i) D += s_e64[i];
            double c = 0.0;
            int Kp = 0;
            #pragma unroll 1
            for (int i = 0; i < Kk; ++i) {
                bool keep = (i == 0) || (c <= 0.9);
                c += s_e64[i] / D;
                if (keep) Kp = i + 1; else break;
            }
            double D2 = 0.0;
            #pragma unroll 1
            for (int i = 0; i < Kp; ++i) D2 += s_e64[i];
            double lse = log(D2);
            s_lse = lse;
            s_rc = (float)((-1e9 - mx) - lse);
            s_kp = Kp;
        }
        halfbar();
        if (tid < s_kp) s_kof[tid] = (float)((s_v64[tid] - mx) - s_lse);
        halfbar();
    };

    // ============================ schedule ============================
    // segment boundaries: streaming crew (12 waves) takes 13/16, mid crew 3/16
    const int nqB   = geomNq(rowB);
    const int q1B   = (nqB * 13) >> 4;
    const int onqA  = geomNq(orowA);
    const int q1A   = (onqA * 13) >> 4;

    // step 1: all waves read A (static partition)
    streamSeg(rowA, s_cv, s_ci, &s_cnt, 0, geomNq(rowA), tid, NT, true);
    __syncthreads();

    // step 2: waves 0-3 mid-A then late 3/16 of read-B; waves 4-15 first 13/16
    if (tid < HNT) {
        midPhasesH(rowA, s_prawA, s_ppenA, s_cv, s_ci, &s_cnt);
        streamSeg(rowB, s_cv2, s_ci2, &s_cnt2, q1B, nqB, tid, HNT, false);
    } else {
        streamSeg(rowB, s_cv2, s_ci2, &s_cnt2, 0, q1B, tid - HNT, SNT, true);
    }
    __syncthreads();

    // step 3: save A results; reset for mid-B
    const float rcA = s_rc;
    const int   kpA = s_kp;
    if (tid < KCAP) { s_kiA[tid] = s_ki[tid]; s_kofA[tid] = s_kof[tid]; }
    if (tid == 0) s_cntinv = 0;
    __syncthreads();

    // step 4: waves 0-3 mid-B then late 3/16 of fill-A; waves 4-15 first 13/16
    if (tid < HNT) {
        midPhasesH(rowB, s_prawB, s_ppenB, s_cv2, s_ci2, &s_cnt2);
        fillSeg(orowA, rcA, q1A, onqA, tid, HNT, false);
    } else {
        fillSeg(orowA, rcA, 0, q1A, tid - HNT, SNT, true);
    }
    __syncthreads();   // drains fills -> scatter-A ordered after; mid-B results ready

    // step 5: scatter A; all waves fill B full-width static; scatter B
    if (tid < kpA) orowA[s_kiA[tid]] = s_kofA[tid];
    const float rcB = s_rc;
    fillSeg(orowB, rcB, 0, geomNq(orowB), tid, NT, true);
    __syncthreads();   // drain fill-B before scatter
    if (tid < s_kp) orowB[s_ki[tid]] = s_kof[tid];
}

extern "C" void kernel_launch(void* const* d_in, const int* in_sizes, int n_in,
                              void* d_out, int out_size, void* d_ws, size_t ws_size,
                              hipStream_t stream) {
    const float* logits = (const float*)d_in[0];
    const int*   prev   = (const int*)d_in[1];
    float*       out    = (float*)d_out;
    dim3 grid(NBLK), block(NT);
    hipLaunchKernelGGL(sch_kernel, grid, block, 0, stream, logits, prev, out);
}

// Round 13
// 89.986 us; speedup vs baseline: 1.4891x; 1.4891x over previous
//
#include <hip/hip_runtime.h>
#include <cstdint>
#include <cfloat>
#include <math.h>

// Problem constants (match reference)
#define BB 16
#define SS 64
#define VV 50257
#define PP 64

#define NT 1024         // threads per block (16 waves; 2 blocks/CU -> 32 waves/CU)
#define HNT 512         // half-block (waves 0-7) running the mid phases
#define NBLK 512        // block g handles rows g and g+512 (same s, same prev!)
#define BINS 2048       // key histogram bins (top 11 bits of ordered key)
#define CAP 1536        // candidate buffer capacity
#define BMW 1572        // bitmap words: ceil(50257/32)=1571 (+1 pad)
#define KCAP 128        // kept (top-k survivors) capacity
#define BCAP 512        // kth-bin member list capacity
#define TRAW 6.0f       // raw-domain candidate threshold (= 7.5 scaled * 0.8)

// RULES LEARNED (R11/R12, both regressed):
//  - never put an atomic/shfl in the stream address path (kills MLP)
//  - one linear stream per row per epoch; two crews splitting one row's
//    fill/read inflates WRITE_SIZE 208->259MB + FETCH 104->113MB (WC defeat)

typedef float f32x4 __attribute__((ext_vector_type(4)));

// monotone float->uint key (increasing)
__device__ __forceinline__ uint32_t fkey(float f) {
    uint32_t u = __float_as_uint(f);
    return u ^ ((uint32_t)((int32_t)u >> 31) | 0x80000000u);
}
__device__ __forceinline__ float key2f(uint32_t u) {
    uint32_t b = (u & 0x80000000u) ? (u ^ 0x80000000u) : ~u;
    return __uint_as_float(b);
}

__global__ __launch_bounds__(NT)
void sch_kernel(const float* __restrict__ logits,
                const int* __restrict__ prev,
                float* __restrict__ out)
{
    const int g   = blockIdx.x;            // 0..511
    const int rA  = g;
    const int rB  = g + NBLK;
    const int s   = g % SS;                // rA%SS == rB%SS (512 % 64 == 0)
    const int bA  = rA / SS;
    const int bB  = rB / SS;
    const int tid = threadIdx.x;
    const float* rowA  = logits + (size_t)rA * VV;
    const float* rowB  = logits + (size_t)rB * VV;
    float*       orowA = out    + (size_t)rA * VV;
    float*       orowB = out    + (size_t)rB * VV;

    __shared__ uint32_t s_bm[BMW];
    __shared__ float    s_cv[CAP];    // row-A candidates (pre-temperature domain)
    __shared__ int      s_ci[CAP];
    __shared__ float    s_cv2[CAP];   // row-B candidates
    __shared__ int      s_ci2[CAP];
    __shared__ uint32_t s_hist[BINS];
    __shared__ uint32_t s_scan[16];   // 8 half-wave totals + 8 prefixes
    __shared__ int      s_ptok[PP];
    __shared__ int      s_pneg[PP];   // all_neg flag (same for both rows: same s)
    __shared__ float    s_prawA[PP];
    __shared__ float    s_prawB[PP];
    __shared__ float    s_ppenA[PP];
    __shared__ float    s_ppenB[PP];
    __shared__ float    s_binv[BCAP];
    __shared__ double   s_v64[KCAP];
    __shared__ double   s_e64[KCAP];
    __shared__ int      s_ki[KCAP];
    __shared__ float    s_kof[KCAP];
    __shared__ int      s_kiA[KCAP];  // saved row-A scatter list
    __shared__ float    s_kofA[KCAP];
    __shared__ int    s_cnt, s_cnt2, s_cntinv, s_b50, s_need, s_cntb, s_k50, s_kp, s_Kk;
    __shared__ int    s_hbar;         // half-barrier counter (monotone)
    __shared__ float  s_kth, s_rc;
    __shared__ double s_lse;

    // ---------------- phase 0: penalty setup, ONCE for both rows ----------------
    for (int i = tid; i < BMW; i += NT) s_bm[i] = 0u;
    if (tid < PP) s_pneg[tid] = 1;
    if (tid == 0) { s_cnt = 0; s_cnt2 = 0; s_cntinv = 0; s_hbar = 0; }
    __syncthreads();
    for (int pair = tid; pair < PP * BB; pair += NT) {
        int ti = pair & (PP - 1);
        int b2 = pair >> 6;
        int tok = prev[s * PP + ti];
        float gg = logits[((size_t)b2 * SS + s) * (size_t)VV + tok];
        if (gg >= 0.f) atomicAnd(&s_pneg[ti], 0);
        if (b2 == 0)  s_ptok[ti]  = tok;
        if (b2 == bA) s_prawA[ti] = gg;
        if (b2 == bB) s_prawB[ti] = gg;
    }
    __syncthreads();
    if (tid < PP) {
        int neg = s_pneg[tid];
        float ga = s_prawA[tid], gb = s_prawB[tid];
        s_ppenA[tid] = neg ? (ga * 1.2f) : (ga / 1.2f);
        s_ppenB[tid] = neg ? (gb * 1.2f) : (gb / 1.2f);
        int tok = s_ptok[tid];
        atomicOr(&s_bm[tok >> 5], 1u << (tok & 31));
    }
    __syncthreads();

    // ---------------- half-barrier (waves 0-7 only; spin on LDS) ----------------
    int hb_phase = 0;
    auto halfbar = [&]() {
        __threadfence_block();
        if ((tid & 63) == 0) atomicAdd(&s_hbar, 1);
        ++hb_phase;
        while (*(volatile int*)&s_hbar < 8 * hb_phase)
            __builtin_amdgcn_s_sleep(1);
        __threadfence_block();
    };

    // ---------------- generic helpers ----------------
    auto kbit = [&](int t) -> uint32_t {
        return (s_bm[t >> 5] >> (t & 31)) & 1u;
    };
    auto addRawP = [&](int t, float raw, float* cv, int* ci, int* pcnt) {
        if (raw >= TRAW) {
            int pos = atomicAdd(pcnt, 1);
            if (pos < CAP) { cv[pos] = raw; ci[pos] = t; }
        }
    };
    // barrier-free hot read stream, parameterized thread range [t0, nthr)
    auto streamFastP = [&](const float* row_, float* cv, int* ci, int* pcnt,
                           int t0, int nthr) {
        const int mis   = (int)(((size_t)row_ >> 2) & 3);
        const int head  = (4 - mis) & 3;
        const int nq    = (VV - head) >> 2;
        const int ttail = head + (nq << 2);
        const float4* p4 = reinterpret_cast<const float4*>(row_ + head);
        for (int t = t0; t < head; t += nthr) addRawP(t, row_[t], cv, ci, pcnt);
        int base = 0;
        for (; base + 4 * nthr <= nq; base += 4 * nthr) {
            float4 f[4];
            #pragma unroll
            for (int u = 0; u < 4; ++u) f[u] = p4[base + t0 + u * nthr];
            #pragma unroll
            for (int u = 0; u < 4; ++u) {
                int t = head + ((base + t0 + u * nthr) << 2);
                addRawP(t + 0, f[u].x, cv, ci, pcnt);
                addRawP(t + 1, f[u].y, cv, ci, pcnt);
                addRawP(t + 2, f[u].z, cv, ci, pcnt);
                addRawP(t + 3, f[u].w, cv, ci, pcnt);
            }
        }
        for (int q = base + t0; q < nq; q += nthr) {
            float4 f = p4[q];
            int t = head + (q << 2);
            addRawP(t + 0, f.x, cv, ci, pcnt);
            addRawP(t + 1, f.y, cv, ci, pcnt);
            addRawP(t + 2, f.z, cv, ci, pcnt);
            addRawP(t + 3, f.w, cv, ci, pcnt);
        }
        for (int t = ttail + t0; t < VV; t += nthr) addRawP(t, row_[t], cv, ci, pcnt);
    };
    // barrier-free nt fill, parameterized thread range
    auto ntFill = [&](float* orow_, float rc_, int t0, int nthr) {
        const int omis   = (int)(((size_t)orow_ >> 2) & 3);
        const int ohead  = (4 - omis) & 3;
        const int onq    = (VV - ohead) >> 2;
        const int ottail = ohead + (onq << 2);
        f32x4* o4 = reinterpret_cast<f32x4*>(orow_ + ohead);
        f32x4 rc4; rc4.x = rc_; rc4.y = rc_; rc4.z = rc_; rc4.w = rc_;
        for (int t = t0; t < ohead; t += nthr)
            __builtin_nontemporal_store(rc_, &orow_[t]);
        for (int q = t0; q < onq; q += nthr)
            __builtin_nontemporal_store(rc4, &o4[q]);
        for (int t = ottail + t0; t < VV; t += nthr)
            __builtin_nontemporal_store(rc_, &orow_[t]);
    };

    // ======== half-width (waves 0-7, halfbar-synced) mid-phase machinery ========
    auto procFullH = [&](int t, float raw, bool doHist, float thr, const float* ppenS,
                         float* cv, int* ci, int* pcnt) {
        float v = raw;
        if (kbit(t)) {
            #pragma unroll 1
            for (int j = 0; j < PP; ++j)
                if (s_ptok[j] == t) { v = ppenS[j]; break; }
        }
        if (!doHist) {
            if (v >= thr) {
                int pos = atomicAdd(pcnt, 1);
                if (pos < CAP) { cv[pos] = v; ci[pos] = t; }
            }
        } else {
            atomicAdd(&s_hist[fkey(v) >> 21], 1u);
        }
    };
    auto streamFullH = [&](bool doHist, float thr, const float* row_, const float* ppenS,
                           float* cv, int* ci, int* pcnt) {
        const int mis   = (int)(((size_t)row_ >> 2) & 3);
        const int head  = (4 - mis) & 3;
        const int nq    = (VV - head) >> 2;
        const int ttail = head + (nq << 2);
        const float4* p4 = reinterpret_cast<const float4*>(row_ + head);
        for (int t = tid; t < head; t += HNT) procFullH(t, row_[t], doHist, thr, ppenS, cv, ci, pcnt);
        for (int q = tid; q < nq; q += HNT) {
            float4 f = p4[q];
            int t = head + (q << 2);
            procFullH(t + 0, f.x, doHist, thr, ppenS, cv, ci, pcnt);
            procFullH(t + 1, f.y, doHist, thr, ppenS, cv, ci, pcnt);
            procFullH(t + 2, f.z, doHist, thr, ppenS, cv, ci, pcnt);
            procFullH(t + 3, f.w, doHist, thr, ppenS, cv, ci, pcnt);
        }
        for (int t = ttail + tid; t < VV; t += HNT) procFullH(t, row_[t], doHist, thr, ppenS, cv, ci, pcnt);
    };
    auto findB50H = [&](int target) {
        halfbar();                           // histogram complete
        const int per = BINS / HNT;          // 4 bins per thread
        int base = tid * per;
        uint32_t loc = 0;
        #pragma unroll
        for (int k2 = 0; k2 < per; ++k2) loc += s_hist[base + k2];
        uint32_t incl = loc;
        #pragma unroll
        for (int off = 1; off < 64; off <<= 1) {
            uint32_t u = (uint32_t)__shfl_up((int)incl, off, 64);
            if ((tid & 63) >= off) incl += u;
        }
        int wid = tid >> 6;                  // 0..7
        if ((tid & 63) == 63) s_scan[wid] = incl;
        halfbar();
        if (tid < 8) {
            uint32_t p = 0;
            for (int w = 0; w < tid; ++w) p += s_scan[w];
            s_scan[8 + tid] = p;
        }
        halfbar();
        uint32_t pre_incl = s_scan[8 + wid] + incl;
        uint32_t total    = s_scan[8 + 7] + s_scan[7];
        uint32_t run = total - pre_incl;
        for (int k2 = per - 1; k2 >= 0; --k2) {
            uint32_t h = s_hist[base + k2];
            uint32_t run2 = run + h;
            if (run < (uint32_t)target && run2 >= (uint32_t)target) {
                s_b50 = base + k2;
                s_need = target - (int)run;
            }
            run = run2;
        }
        halfbar();
    };
    auto doFallbackH = [&](const float* row_, const float* ppenS,
                           float* cv, int* ci, int* pcnt) {
        for (int i = tid; i < BINS; i += HNT) s_hist[i] = 0u;
        halfbar();
        streamFullH(true, 0.f, row_, ppenS, cv, ci, pcnt);
        findB50H(50);
        float thrF = key2f((uint32_t)s_b50 << 21);
        if (tid == 0) *pcnt = 0;
        halfbar();
        streamFullH(false, thrF, row_, ppenS, cv, ci, pcnt);
        halfbar();
    };
    auto computeKthH = [&](float* cv, int* pcnt) {
        for (int i = tid; i < BINS; i += HNT) s_hist[i] = 0u;
        if (tid == 0) { s_cntb = 0; s_kth = -FLT_MAX; }
        halfbar();
        int cc = min(*pcnt, CAP);
        for (int i = tid; i < cc; i += HNT)
            atomicAdd(&s_hist[fkey(cv[i]) >> 21], 1u);
        findB50H(50);
        int b50 = s_b50, need = s_need;
        for (int i = tid; i < cc; i += HNT) {
            if ((int)(fkey(cv[i]) >> 21) == b50) {
                int p = atomicAdd(&s_cntb, 1);
                if (p < BCAP) s_binv[p] = cv[i];
            }
        }
        halfbar();
        int cb = min(s_cntb, BCAP);
        for (int i = tid; i < cb; i += HNT) {
            float vi = s_binv[i];
            int gt = 0, ge = 0;
            for (int j = 0; j < cb; ++j) {
                float vj = s_binv[j];
                gt += (vj > vi);
                ge += (vj >= vi);
            }
            if (gt < need && ge >= need) s_kth = vi;   // benign race: same value
        }
        halfbar();
    };
    // mid phases on waves 0-7 (tid < HNT). Decision arithmetic identical to R3+.
    auto midPhasesH = [&](const float* row_, const float* prawS, const float* ppenS,
                          float* cv, int* ci, int* pcnt) {
        const int cntRaw = min(*pcnt, CAP);
        for (int i = tid; i < cntRaw; i += HNT) {
            if (kbit(ci[i])) {
                cv[i] = -FLT_MAX;
                atomicAdd(&s_cntinv, 1);
            }
        }
        halfbar();
        if (tid < PP) {
            int tok = s_ptok[tid];
            bool first = true;
            for (int j = 0; j < tid; ++j)
                if (s_ptok[j] == tok) { first = false; break; }
            if (first) {
                int pos = atomicAdd(pcnt, 1);
                if (pos < CAP) { cv[pos] = ppenS[tid]; ci[pos] = tok; }
            }
        }
        halfbar();
        bool fellback = false;
        {
            bool okc = (*pcnt <= CAP) && ((cntRaw - s_cntinv) >= 50);
            if (!okc) { doFallbackH(row_, ppenS, cv, ci, pcnt); fellback = true; }
        }
        computeKthH(cv, pcnt);
        if (!fellback && (s_kth - 1e-4f < TRAW)) {
            doFallbackH(row_, ppenS, cv, ci, pcnt);
            computeKthH(cv, pcnt);
        }
        if (tid == 0) s_k50 = 0;
        halfbar();
        const float gthr = s_kth - 1e-4f;
        const int cntc = min(*pcnt, CAP);
        for (int i = tid; i < cntc; i += HNT) {
            if (cv[i] >= gthr) {
                int p = atomicAdd(&s_k50, 1);
                if (p < KCAP) {
                    int tok = ci[i];
                    double v64;
                    if (kbit(tok)) {
                        int pj = 0;
                        #pragma unroll 1
                        for (int j = 0; j < PP; ++j)
                            if (s_ptok[j] == tok) { pj = j; break; }
                        double gd = (double)prawS[pj];
                        double pen = s_pneg[pj] ? (gd * 1.2) : (gd / 1.2);
                        v64 = pen / 0.8;
                    } else {
                        v64 = (double)cv[i] / 0.8;
                    }
                    s_v64[p] = v64;
                    s_ki[p]  = tok;
                }
            }
        }
        halfbar();
        const int k50c = min(s_k50, KCAP);
        for (int i = k50c + tid; i < KCAP; i += HNT) {
            s_v64[i] = -1e300;
            s_ki[i]  = (1 << 30) + i;
        }
        halfbar();
        // single-wave register bitonic sort (identical comparator)
        if (tid < 64) {
            int l = tid;
            double v0 = s_v64[l],    v1 = s_v64[l + 64];
            int    i0 = s_ki[l],     i1 = s_ki[l + 64];
            for (int k = 2; k <= KCAP; k <<= 1) {
                for (int j = k >> 1; j > 0; j >>= 1) {
                    if (j >= 64) {
                        bool before = (v0 > v1) || (v0 == v1 && i0 < i1);
                        if (!before) {
                            double tv = v0; v0 = v1; v1 = tv;
                            int    ti = i0; i0 = i1; i1 = ti;
                        }
                    } else {
                        double nv0 = __shfl_xor(v0, j, 64);
                        double nv1 = __shfl_xor(v1, j, 64);
                        int    ni0 = __shfl_xor(i0, j, 64);
                        int    ni1 = __shfl_xor(i1, j, 64);
                        bool lower = ((l & j) == 0);
                        bool up0 = ((l & k) == 0);
                        bool up1 = (((l + 64) & k) == 0);
                        bool bm0 = (v0 > nv0) || (v0 == nv0 && i0 < ni0);
                        bool bm1 = (v1 > nv1) || (v1 == nv1 && i1 < ni1);
                        bool keep0 = lower ? (up0 == bm0) : (up0 != bm0);
                        bool keep1 = lower ? (up1 == bm1) : (up1 != bm1);
                        if (!keep0) { v0 = nv0; i0 = ni0; }
                        if (!keep1) { v1 = nv1; i1 = ni1; }
                    }
                }
            }
            s_v64[l] = v0; s_v64[l + 64] = v1;
            s_ki[l]  = i0; s_ki[l + 64]  = i1;
        }
        halfbar();
        if (tid == 0) {
            int kk = k50c;
            int Kkept;
            if (kk <= 50) Kkept = kk;
            else {
                double kth64 = s_v64[49];
                Kkept = 50;
                while (Kkept < kk && s_v64[Kkept] == kth64) ++Kkept;
            }
            s_Kk = Kkept;
        }
        halfbar();
        const int Kk = s_Kk;
        const double mx = s_v64[0];
        if (tid < Kk) s_e64[tid] = exp(s_v64[tid] - mx);
        halfbar();
        if (tid == 0) {
            double D = 0.0;                    // same serial order as reference
            #pragma unroll 1
            for (int i = 0; i < Kk; ++i) D += s_e64[i];
            double c = 0.0;
            int Kp = 0;
            #pragma unroll 1
            for (int i = 0; i < Kk; ++i) {
                bool keep = (i == 0) || (c <= 0.9);
                c += s_e64[i] / D;
                if (keep) Kp = i + 1; else break;
            }
            double D2 = 0.0;
            #pragma unroll 1
            for (int i = 0; i < Kp; ++i) D2 += s_e64[i];
            double lse = log(D2);
            s_lse = lse;
            s_rc = (float)((-1e9 - mx) - lse);
            s_kp = Kp;
        }
        halfbar();
        if (tid < s_kp) s_kof[tid] = (float)((s_v64[tid] - mx) - s_lse);
        halfbar();
    };

    // ============================ schedule (R10, measured best) ============================
    // step 1: all waves read A
    streamFastP(rowA, s_cv, s_ci, &s_cnt, tid, NT);
    __syncthreads();

    // step 2: w0-7 mid-A  ∥  w8-15 read B (each crew owns a whole stream)
    if (tid < HNT) {
        midPhasesH(rowA, s_prawA, s_ppenA, s_cv, s_ci, &s_cnt);
    } else {
        streamFastP(rowB, s_cv2, s_ci2, &s_cnt2, tid - HNT, HNT);
    }
    __syncthreads();

    // step 3: save A results; reset for mid-B
    const float rcA = s_rc;
    const int   kpA = s_kp;
    if (tid < KCAP) { s_kiA[tid] = s_ki[tid]; s_kofA[tid] = s_kof[tid]; }
    if (tid == 0) s_cntinv = 0;
    __syncthreads();

    // step 4: w0-7 mid-B  ∥  w8-15 nt-fill A (whole row, single linear stream)
    if (tid < HNT) {
        midPhasesH(rowB, s_prawB, s_ppenB, s_cv2, s_ci2, &s_cnt2);
    } else {
        ntFill(orowA, rcA, tid - HNT, HNT);
    }
    __syncthreads();   // each wave drains its own vmcnt before s_barrier -> fill-A done

    // step 5: scatter A, then all waves fill B + scatter B
    if (tid < kpA) orowA[s_kiA[tid]] = s_kofA[tid];
    const float rcB = s_rc;
    ntFill(orowB, rcB, tid, NT);
    __syncthreads();   // drain fill-B before scatter
    if (tid < s_kp) orowB[s_ki[tid]] = s_kof[tid];
}

extern "C" void kernel_launch(void* const* d_in, const int* in_sizes, int n_in,
                              void* d_out, int out_size, void* d_ws, size_t ws_size,
                              hipStream_t stream) {
    const float* logits = (const float*)d_in[0];
    const int*   prev   = (const int*)d_in[1];
    float*       out    = (float*)d_out;
    dim3 grid(NBLK), block(NT);
    hipLaunchKernelGGL(sch_kernel, grid, block, 0, stream, logits, prev, out);
}